// Round 3
// baseline (169.214 us; speedup 1.0000x reference)
//
#include <hip/hip_runtime.h>

// BoundaryAwareLoss = dice(pred,target) + bce(sigmoid(pred)*boundary, target*boundary)
// boundary = 15x15 dilate - erode (clipped windows == clamp-to-edge).
// BCE broadcast (B,B,H,W) factors per pixel: sum_{b1,b2} bd[b1]*f[b2] = cnt*F,
// with bd==0 pixels contributing exactly 0. Two-phase to parallelize over batch.

#define BB   8
#define HH   544
#define WW   544
#define HWS  (HH * WW)          // 295936
#define KK   15
#define PADR 7
#define TH   32
#define TW   32
#define SR   (TH + 2*PADR)      // 46
#define SC   (TW + 2*PADR)      // 46
#define SCP  48

// ---------------- phase 1: per-(batch,tile) boundary + BCE term ----------------
__global__ __launch_bounds__(256) void ba_phase1(
    const float* __restrict__ pred, const float* __restrict__ targ,
    float* __restrict__ acc, float* __restrict__ farr,
    unsigned char* __restrict__ bdarr)
{
    __shared__ float sh_t[SR][SCP];
    __shared__ float hmx[SR][TW + 1];
    __shared__ float hmn[SR][TW + 1];
    __shared__ float red[4][3];

    const int x0 = blockIdx.x * TW;
    const int y0 = blockIdx.y * TH;
    const int b  = blockIdx.z;
    const int tid = threadIdx.x;
    const int tx = tid & 31, ty = tid >> 5;

    const float* tb = targ + (size_t)b * HWS;
    const float* pb = pred + (size_t)b * HWS;

    // stage target tile + halo (clamp-to-edge == clipped window)
    for (int i = tid; i < SR * SC; i += 256) {
        int r = i / SC, c = i - r * SC;
        int gy = y0 - PADR + r; gy = gy < 0 ? 0 : (gy > HH - 1 ? HH - 1 : gy);
        int gx = x0 - PADR + c; gx = gx < 0 ? 0 : (gx > WW - 1 ? WW - 1 : gx);
        sh_t[r][c] = tb[gy * WW + gx];
    }
    __syncthreads();

    // horizontal 15-tap max/min
    for (int i = tid; i < SR * TW; i += 256) {
        int r = i >> 5, c = i & 31;
        float mx = sh_t[r][c], mn = mx;
        #pragma unroll
        for (int j = 1; j < KK; ++j) {
            float v = sh_t[r][c + j];
            mx = fmaxf(mx, v);
            mn = fminf(mn, v);
        }
        hmx[r][c] = mx;
        hmn[r][c] = mn;
    }
    __syncthreads();

    // vertical 15-tap + per-pixel terms, 4 rows/thread
    float sp = 0.f, st = 0.f, si = 0.f;
    #pragma unroll
    for (int k = 0; k < 4; ++k) {
        int ly = ty + k * 8;
        int gy = y0 + ly, gx = x0 + tx;
        float mx = hmx[ly][tx], mn = hmn[ly][tx];
        #pragma unroll
        for (int j = 1; j < KK; ++j) {
            mx = fmaxf(mx, hmx[ly + j][tx]);
            mn = fminf(mn, hmn[ly + j][tx]);
        }
        float bd = mx - mn;                       // 0 or 1
        float p  = pb[gy * WW + gx];
        float tt = sh_t[ly + PADR][tx + PADR];
        sp += p; st += tt; si += p * tt;
        // f = t*log(sig(p)) + (1-t)*log(1-sig(p)), clamped at -100 (stable softplus)
        float a   = log1pf(expf(-fabsf(p)));
        float lp  = fmaxf(-(fmaxf(-p, 0.f) + a), -100.f);
        float l1p = fmaxf(-(fmaxf( p, 0.f) + a), -100.f);
        float f   = tt * lp + (1.f - tt) * l1p;
        size_t o = (size_t)b * HWS + (size_t)gy * WW + gx;
        farr[o]  = f;
        bdarr[o] = (unsigned char)(bd > 0.5f);
    }

    // block-reduce dice partials
    #pragma unroll
    for (int off = 32; off > 0; off >>= 1) {
        sp += __shfl_down(sp, off);
        st += __shfl_down(st, off);
        si += __shfl_down(si, off);
    }
    int wave = tid >> 6, lane = tid & 63;
    if (lane == 0) { red[wave][0] = sp; red[wave][1] = st; red[wave][2] = si; }
    __syncthreads();
    if (tid == 0) {
        float a0 = 0.f, a1 = 0.f, a2 = 0.f;
        #pragma unroll
        for (int w = 0; w < 4; ++w) { a0 += red[w][0]; a1 += red[w][1]; a2 += red[w][2]; }
        atomicAdd(&acc[0], a0);
        atomicAdd(&acc[1], a1);
        atomicAdd(&acc[2], a2);
    }
}

// ---------------- phase 2: sum_hw (sum_b bd) * (sum_b f) ----------------
__global__ __launch_bounds__(256) void ba_phase2(
    const float* __restrict__ farr, const unsigned char* __restrict__ bdarr,
    float* __restrict__ acc)
{
    __shared__ float red[4];
    int i = blockIdx.x * 256 + threadIdx.x;     // 73984 threads, 4 px each (exact)
    int px = i * 4;
    float c0 = 0.f, c1 = 0.f, c2 = 0.f, c3 = 0.f;
    float F0 = 0.f, F1 = 0.f, F2 = 0.f, F3 = 0.f;
    #pragma unroll
    for (int b = 0; b < BB; ++b) {
        uchar4 u = *(const uchar4*)(bdarr + (size_t)b * HWS + px);
        float4 f = *(const float4*)(farr  + (size_t)b * HWS + px);
        c0 += u.x; c1 += u.y; c2 += u.z; c3 += u.w;
        F0 += f.x; F1 += f.y; F2 += f.z; F3 += f.w;
    }
    float sum = c0 * F0 + c1 * F1 + c2 * F2 + c3 * F3;

    #pragma unroll
    for (int off = 32; off > 0; off >>= 1) sum += __shfl_down(sum, off);
    int wave = threadIdx.x >> 6, lane = threadIdx.x & 63;
    if (lane == 0) red[wave] = sum;
    __syncthreads();
    if (threadIdx.x == 0)
        atomicAdd(&acc[3], red[0] + red[1] + red[2] + red[3]);
}

__global__ void ba_final(const float* __restrict__ acc, float* __restrict__ out)
{
    if (threadIdx.x == 0) {
        float sp = acc[0], st = acc[1], si = acc[2], bs = acc[3];
        float dice = 1.f - (2.f * si + 1.f) / (sp + st + 1.f);
        float bce  = -bs / (float)((long long)BB * BB * HH * WW);
        out[0] = dice + bce;
    }
}

extern "C" void kernel_launch(void* const* d_in, const int* in_sizes, int n_in,
                              void* d_out, int out_size, void* d_ws, size_t ws_size,
                              hipStream_t stream) {
    const float* pred = (const float*)d_in[0];
    const float* targ = (const float*)d_in[1];
    float* out = (float*)d_out;

    float* acc = (float*)d_ws;
    float* farr = (float*)((char*)d_ws + 16);
    unsigned char* bdarr = (unsigned char*)((char*)d_ws + 16 + (size_t)BB * HWS * 4);

    hipMemsetAsync(acc, 0, 4 * sizeof(float), stream);

    dim3 g1(WW / TW, HH / TH, BB);                 // 17 x 17 x 8
    ba_phase1<<<g1, 256, 0, stream>>>(pred, targ, acc, farr, bdarr);
    ba_phase2<<<HWS / 4 / 256, 256, 0, stream>>>(farr, bdarr, acc);  // 289 blocks
    ba_final<<<1, 64, 0, stream>>>(acc, out);
}

// Round 4
// 91.035 us; speedup vs baseline: 1.8588x; 1.8588x over previous
//
#include <hip/hip_runtime.h>

// BoundaryAwareLoss = dice(pred,target) + bce(sigmoid(pred)*boundary, target*boundary)
// boundary = 15x15 (dilate - erode) of binary target, clipped windows == clamp-to-edge.
// BCE broadcast (B,B,H,W) factors per pixel:
//   sum_{b1,b2} bd[b1,px]*f[b2,px] = cnt(px) * F(px),  cnt = sum_b bd, F = sum_b f,
// and bd==0 pixels contribute exactly 0 (verified absmax 0.0 in rounds 1,3).
// target is binary -> pack 8 batches as bits in one byte/pixel:
//   horizontal max/min -> 2 packed bytes; vertical max = bytewise OR, min = AND;
//   cnt(px) = popcount(or & ~and). All kernels are flat streaming ops, no atomics.

#define BB   8
#define HH   544
#define WW   544
#define HWS  (HH * WW)          // 295936
#define HWU  (HWS / 4)          // 73984 (uint-of-4-pixels count)
#define ROWU (WW / 4)           // 136
#define KK   15
#define PADR 7
#define NB2  (BB * HWU / 256)   // 2312 K2 blocks

// ---- K1a: horizontal 15-tap max/min, all 8 batches, bit-packed output ----
__global__ __launch_bounds__(256) void ba_k1a(
    const float* __restrict__ targ,
    unsigned char* __restrict__ hmxb, unsigned char* __restrict__ hmnb)
{
    __shared__ float sh[BB][288];            // 272 px + 14 halo = 286 staged
    const int y   = blockIdx.y;
    const int px0 = blockIdx.x * 272;
    const int tid = threadIdx.x;

    for (int j = tid; j < BB * 286; j += 256) {
        int b = j / 286, k = j - b * 286;
        int gx = px0 - PADR + k; gx = gx < 0 ? 0 : (gx > WW - 1 ? WW - 1 : gx);
        sh[b][k] = targ[(size_t)b * HWS + y * WW + gx];
    }
    __syncthreads();

    for (int i = tid; i < 272; i += 256) {
        unsigned int mx = 0, mn = 0;
        #pragma unroll
        for (int b = 0; b < BB; ++b) {
            float vmx = sh[b][i], vmn = vmx;
            #pragma unroll
            for (int j = 1; j < KK; ++j) {
                float v = sh[b][i + j];
                vmx = fmaxf(vmx, v);
                vmn = fminf(vmn, v);
            }
            mx |= (vmx > 0.5f ? 1u : 0u) << b;
            mn |= (vmn > 0.5f ? 1u : 0u) << b;
        }
        int px = y * WW + px0 + i;
        hmxb[px] = (unsigned char)mx;
        hmnb[px] = (unsigned char)mn;
    }
}

// ---- K1b: vertical 15-tap via bytewise OR/AND on uints; cnt = popcount/byte ----
__global__ __launch_bounds__(256) void ba_k1b(
    const unsigned char* __restrict__ hmxb, const unsigned char* __restrict__ hmnb,
    unsigned char* __restrict__ cntb)
{
    int u = blockIdx.x * 256 + threadIdx.x;          // < 73984, exact
    int y = u / ROWU, xu = u - y * ROWU;
    const unsigned int* mxU = (const unsigned int*)hmxb;
    const unsigned int* mnU = (const unsigned int*)hmnb;
    unsigned int orv = 0u, andv = 0xFFFFFFFFu;
    #pragma unroll
    for (int j = 0; j < KK; ++j) {
        int yy = y - PADR + j; yy = yy < 0 ? 0 : (yy > HH - 1 ? HH - 1 : yy);
        orv  |= mxU[yy * ROWU + xu];
        andv &= mnU[yy * ROWU + xu];
    }
    unsigned int mask = orv & ~andv;                 // bd bits per pixel-byte
    unsigned int c = (unsigned int)__popc(mask & 0xFFu)
                   | ((unsigned int)__popc((mask >> 8)  & 0xFFu) << 8)
                   | ((unsigned int)__popc((mask >> 16) & 0xFFu) << 16)
                   | ((unsigned int)__popc(mask >> 24) << 24);
    ((unsigned int*)cntb)[u] = c;
}

// ---- K2: streaming BCE-term + dice partials, per-block partial sums ----
__global__ __launch_bounds__(256) void ba_k2(
    const float* __restrict__ pred, const float* __restrict__ targ,
    const unsigned char* __restrict__ cntb, float4* __restrict__ partials)
{
    __shared__ float red[4][4];
    int i = blockIdx.x * 256 + threadIdx.x;          // < 591872, exact
    int plane = i / HWU;
    int u = i - plane * HWU;
    const float4 p4 = *(const float4*)(pred + (size_t)plane * HWS + 4 * (size_t)u);
    const float4 t4 = *(const float4*)(targ + (size_t)plane * HWS + 4 * (size_t)u);
    unsigned int c4 = ((const unsigned int*)cntb)[u];

    float sp = 0.f, st = 0.f, si = 0.f, bs = 0.f;
    const float* pv = (const float*)&p4;
    const float* tv = (const float*)&t4;
    #pragma unroll
    for (int k = 0; k < 4; ++k) {
        float p  = pv[k];
        float tt = tv[k];
        float cn = (float)((c4 >> (8 * k)) & 0xFFu);
        sp += p; st += tt; si += p * tt;
        // f = t*max(log(sig(p)),-100) + (1-t)*max(log(1-sig(p)),-100), stable softplus
        float a   = log1pf(expf(-fabsf(p)));
        float lp  = fmaxf(-(fmaxf(-p, 0.f) + a), -100.f);
        float l1p = fmaxf(-(fmaxf( p, 0.f) + a), -100.f);
        bs += cn * (tt * lp + (1.f - tt) * l1p);
    }

    #pragma unroll
    for (int off = 32; off > 0; off >>= 1) {
        sp += __shfl_down(sp, off);
        st += __shfl_down(st, off);
        si += __shfl_down(si, off);
        bs += __shfl_down(bs, off);
    }
    int wave = threadIdx.x >> 6, lane = threadIdx.x & 63;
    if (lane == 0) {
        red[wave][0] = sp; red[wave][1] = st; red[wave][2] = si; red[wave][3] = bs;
    }
    __syncthreads();
    if (threadIdx.x == 0) {
        float a0 = 0.f, a1 = 0.f, a2 = 0.f, a3 = 0.f;
        #pragma unroll
        for (int w = 0; w < 4; ++w) {
            a0 += red[w][0]; a1 += red[w][1]; a2 += red[w][2]; a3 += red[w][3];
        }
        partials[blockIdx.x] = make_float4(a0, a1, a2, a3);
    }
}

// ---- final: sum partials, compose loss ----
__global__ __launch_bounds__(256) void ba_final(
    const float4* __restrict__ partials, float* __restrict__ out)
{
    __shared__ float red[4][4];
    float sp = 0.f, st = 0.f, si = 0.f, bs = 0.f;
    for (int i = threadIdx.x; i < NB2; i += 256) {
        float4 v = partials[i];
        sp += v.x; st += v.y; si += v.z; bs += v.w;
    }
    #pragma unroll
    for (int off = 32; off > 0; off >>= 1) {
        sp += __shfl_down(sp, off);
        st += __shfl_down(st, off);
        si += __shfl_down(si, off);
        bs += __shfl_down(bs, off);
    }
    int wave = threadIdx.x >> 6, lane = threadIdx.x & 63;
    if (lane == 0) {
        red[wave][0] = sp; red[wave][1] = st; red[wave][2] = si; red[wave][3] = bs;
    }
    __syncthreads();
    if (threadIdx.x == 0) {
        float a0 = 0.f, a1 = 0.f, a2 = 0.f, a3 = 0.f;
        #pragma unroll
        for (int w = 0; w < 4; ++w) {
            a0 += red[w][0]; a1 += red[w][1]; a2 += red[w][2]; a3 += red[w][3];
        }
        float dice = 1.f - (2.f * a2 + 1.f) / (a0 + a1 + 1.f);
        float bce  = -a3 / (float)((long long)BB * BB * HH * WW);
        out[0] = dice + bce;
    }
}

extern "C" void kernel_launch(void* const* d_in, const int* in_sizes, int n_in,
                              void* d_out, int out_size, void* d_ws, size_t ws_size,
                              hipStream_t stream) {
    const float* pred = (const float*)d_in[0];
    const float* targ = (const float*)d_in[1];
    float* out = (float*)d_out;

    unsigned char* hmxb = (unsigned char*)d_ws;
    unsigned char* hmnb = hmxb + HWS;
    unsigned char* cntb = hmnb + HWS;
    float4* partials = (float4*)(cntb + HWS);        // 2312 * 16 B

    ba_k1a<<<dim3(2, HH), 256, 0, stream>>>(targ, hmxb, hmnb);
    ba_k1b<<<HWU / 256, 256, 0, stream>>>(hmxb, hmnb, cntb);     // 289 blocks
    ba_k2<<<NB2, 256, 0, stream>>>(pred, targ, cntb, partials);  // 2312 blocks
    ba_final<<<1, 256, 0, stream>>>(partials, out);
}

// Round 5
// 82.283 us; speedup vs baseline: 2.0565x; 1.1064x over previous
//
#include <hip/hip_runtime.h>

// BoundaryAwareLoss = dice(pred,target) + bce(sigmoid(pred)*boundary, target*boundary)
// boundary = 15x15 (dilate - erode) of binary target, clipped windows == clamp-to-edge.
// BCE broadcast (B,B,H,W) factors per pixel:
//   sum_{b1,b2} bd[b1,px]*f[b2,px] = cnt(px) * F(px),  cnt = sum_b bd, F = sum_b f,
// and bd==0 pixels contribute exactly 0 (absmax 0.0 in rounds 1,3,4).
// target is binary -> pack 8 batches as bits in one byte/pixel:
//   horizontal max/min -> 2 packed bytes (K1); vertical max = bytewise OR, min = AND,
//   computed inline in K2; cnt(px) = popcount(or & ~and).
// 3 dispatches: K1 (h-pass, bit-pack) -> K2 (v-pass + BCE/dice stream) -> final.

#define BB   8
#define HH   544
#define WW   544
#define HWS  (HH * WW)          // 295936
#define HWU  (HWS / 4)          // 73984 uint-of-4-pixels
#define ROWU (WW / 4)           // 136
#define KK   15
#define PADR 7
#define NBX  (HWU / 256)        // 289
#define NB2  (NBX * BB)         // 2312 partials

// ---- K1: horizontal 15-tap max/min, all 8 batches, bit-packed bytes ----
__global__ __launch_bounds__(256) void ba_k1(
    const float* __restrict__ targ,
    unsigned char* __restrict__ hmxb, unsigned char* __restrict__ hmnb)
{
    __shared__ float sh[BB][288];            // 272 out px + 14 halo = 286 staged
    const int y   = blockIdx.y;
    const int px0 = blockIdx.x * 272;
    const int tid = threadIdx.x;

    for (int j = tid; j < BB * 286; j += 256) {
        int b = j / 286, k = j - b * 286;
        int gx = px0 - PADR + k; gx = gx < 0 ? 0 : (gx > WW - 1 ? WW - 1 : gx);
        sh[b][k] = targ[(size_t)b * HWS + y * WW + gx];
    }
    __syncthreads();

    for (int i = tid; i < 272; i += 256) {
        unsigned int mx = 0, mn = 0;
        #pragma unroll
        for (int b = 0; b < BB; ++b) {
            float vmx = sh[b][i], vmn = vmx;
            #pragma unroll
            for (int j = 1; j < KK; ++j) {
                float v = sh[b][i + j];
                vmx = fmaxf(vmx, v);
                vmn = fminf(vmn, v);
            }
            mx |= (vmx > 0.5f ? 1u : 0u) << b;
            mn |= (vmn > 0.5f ? 1u : 0u) << b;
        }
        int px = y * WW + px0 + i;
        hmxb[px] = (unsigned char)mx;
        hmnb[px] = (unsigned char)mn;
    }
}

// ---- K2: vertical 15-tap (bytewise OR/AND) + streaming BCE/dice partials ----
__global__ __launch_bounds__(256) void ba_k2(
    const float* __restrict__ pred, const float* __restrict__ targ,
    const unsigned char* __restrict__ hmxb, const unsigned char* __restrict__ hmnb,
    float4* __restrict__ partials)
{
    __shared__ float red[4][4];
    const int plane = blockIdx.y;
    const int u = blockIdx.x * 256 + threadIdx.x;    // < 73984, exact
    const int y = u / ROWU, xu = u - y * ROWU;

    // vertical window: OR of hmx words, AND of hmn words (clamp-to-edge rows)
    const unsigned int* mxU = (const unsigned int*)hmxb;
    const unsigned int* mnU = (const unsigned int*)hmnb;
    unsigned int orv = 0u, andv = 0xFFFFFFFFu;
    #pragma unroll
    for (int j = 0; j < KK; ++j) {
        int yy = y - PADR + j; yy = yy < 0 ? 0 : (yy > HH - 1 ? HH - 1 : yy);
        orv  |= mxU[yy * ROWU + xu];
        andv &= mnU[yy * ROWU + xu];
    }
    const unsigned int mask = orv & ~andv;           // bd bits, byte per pixel

    const float4 p4 = *(const float4*)(pred + (size_t)plane * HWS + 4 * (size_t)u);
    const float4 t4 = *(const float4*)(targ + (size_t)plane * HWS + 4 * (size_t)u);

    float sp = 0.f, st = 0.f, si = 0.f, bs = 0.f;
    const float* pv = (const float*)&p4;
    const float* tv = (const float*)&t4;
    #pragma unroll
    for (int k = 0; k < 4; ++k) {
        float p  = pv[k];
        float tt = tv[k];
        float cn = (float)__popc((mask >> (8 * k)) & 0xFFu);
        sp += p; st += tt; si += p * tt;
        // f = t*max(log(sig(p)),-100) + (1-t)*max(log(1-sig(p)),-100), stable softplus
        float a   = __logf(1.f + __expf(-fabsf(p)));
        float lp  = fmaxf(-(fmaxf(-p, 0.f) + a), -100.f);
        float l1p = fmaxf(-(fmaxf( p, 0.f) + a), -100.f);
        bs += cn * (tt * lp + (1.f - tt) * l1p);
    }

    #pragma unroll
    for (int off = 32; off > 0; off >>= 1) {
        sp += __shfl_down(sp, off);
        st += __shfl_down(st, off);
        si += __shfl_down(si, off);
        bs += __shfl_down(bs, off);
    }
    int wave = threadIdx.x >> 6, lane = threadIdx.x & 63;
    if (lane == 0) {
        red[wave][0] = sp; red[wave][1] = st; red[wave][2] = si; red[wave][3] = bs;
    }
    __syncthreads();
    if (threadIdx.x == 0) {
        float a0 = 0.f, a1 = 0.f, a2 = 0.f, a3 = 0.f;
        #pragma unroll
        for (int w = 0; w < 4; ++w) {
            a0 += red[w][0]; a1 += red[w][1]; a2 += red[w][2]; a3 += red[w][3];
        }
        partials[blockIdx.y * NBX + blockIdx.x] = make_float4(a0, a1, a2, a3);
    }
}

// ---- final: sum partials, compose loss ----
__global__ __launch_bounds__(256) void ba_final(
    const float4* __restrict__ partials, float* __restrict__ out)
{
    __shared__ float red[4][4];
    float sp = 0.f, st = 0.f, si = 0.f, bs = 0.f;
    for (int i = threadIdx.x; i < NB2; i += 256) {
        float4 v = partials[i];
        sp += v.x; st += v.y; si += v.z; bs += v.w;
    }
    #pragma unroll
    for (int off = 32; off > 0; off >>= 1) {
        sp += __shfl_down(sp, off);
        st += __shfl_down(st, off);
        si += __shfl_down(si, off);
        bs += __shfl_down(bs, off);
    }
    int wave = threadIdx.x >> 6, lane = threadIdx.x & 63;
    if (lane == 0) {
        red[wave][0] = sp; red[wave][1] = st; red[wave][2] = si; red[wave][3] = bs;
    }
    __syncthreads();
    if (threadIdx.x == 0) {
        float a0 = 0.f, a1 = 0.f, a2 = 0.f, a3 = 0.f;
        #pragma unroll
        for (int w = 0; w < 4; ++w) {
            a0 += red[w][0]; a1 += red[w][1]; a2 += red[w][2]; a3 += red[w][3];
        }
        float dice = 1.f - (2.f * a2 + 1.f) / (a0 + a1 + 1.f);
        float bce  = -a3 / (float)((long long)BB * BB * HH * WW);
        out[0] = dice + bce;
    }
}

extern "C" void kernel_launch(void* const* d_in, const int* in_sizes, int n_in,
                              void* d_out, int out_size, void* d_ws, size_t ws_size,
                              hipStream_t stream) {
    const float* pred = (const float*)d_in[0];
    const float* targ = (const float*)d_in[1];
    float* out = (float*)d_out;

    unsigned char* hmxb = (unsigned char*)d_ws;
    unsigned char* hmnb = hmxb + HWS;
    float4* partials = (float4*)(hmnb + HWS);        // NB2 * 16 B

    ba_k1<<<dim3(2, HH), 256, 0, stream>>>(targ, hmxb, hmnb);
    ba_k2<<<dim3(NBX, BB), 256, 0, stream>>>(pred, targ, hmxb, hmnb, partials);
    ba_final<<<1, 256, 0, stream>>>(partials, out);
}

// Round 6
// 79.344 us; speedup vs baseline: 2.1327x; 1.0370x over previous
//
#include <hip/hip_runtime.h>

// BoundaryAwareLoss = dice(pred,target) + bce(sigmoid(pred)*boundary, target*boundary)
// boundary = 15x15 (dilate - erode) of binary target, clipped windows == clamp-to-edge.
// BCE broadcast (B,B,H,W) factors per pixel:
//   sum_{b1,b2} bd[b1,px]*f[b2,px] = cnt(px) * F(px),  cnt = sum_b bd, F = sum_b f,
// and bd==0 pixels contribute exactly 0 (absmax 0.0 in rounds 1,3,4,5).
// target binary -> pack 8 batches as bits/byte: h-pass max/min -> 2 bytes (K1);
// v-pass = bytewise OR/AND + popcount (K2). F = sum_b f computed in K1 so HBM
// (19 MB pred+targ) is streamed exactly once; K2 is all-L2 (0.6 MB x15 + 1.2 MB).
// 3 dispatches: K1 (h-pass + F + dice partials) -> K2 (v-pass + cnt.F) -> final.

#define BB   8
#define HH   544
#define WW   544
#define HWS  (HH * WW)          // 295936
#define HWU  (HWS / 4)          // 73984 uint-of-4-pixels
#define ROWU (WW / 4)           // 136
#define KK   15
#define PADR 7
#define NBX  (HWU / 256)        // 289 K2 blocks
#define NB1  (2 * HH)           // 1088 K1 blocks

// ---- K1: horizontal 15-tap max/min (bit-packed) + F = sum_b f + dice partials ----
__global__ __launch_bounds__(256) void ba_k1(
    const float* __restrict__ pred, const float* __restrict__ targ,
    unsigned char* __restrict__ hmxb, unsigned char* __restrict__ hmnb,
    float* __restrict__ Farr, float4* __restrict__ part1)
{
    __shared__ float sh[BB][288];            // 272 out px + 14 halo = 286 staged
    __shared__ float red[4][3];
    const int y   = blockIdx.y;
    const int px0 = blockIdx.x * 272;
    const int tid = threadIdx.x;

    for (int j = tid; j < BB * 286; j += 256) {
        int b = j / 286, k = j - b * 286;
        int gx = px0 - PADR + k; gx = gx < 0 ? 0 : (gx > WW - 1 ? WW - 1 : gx);
        sh[b][k] = targ[(size_t)b * HWS + y * WW + gx];
    }
    __syncthreads();

    float sp = 0.f, st = 0.f, si = 0.f;
    for (int i = tid; i < 272; i += 256) {
        const int px = y * WW + px0 + i;
        unsigned int mx = 0, mn = 0;
        float F = 0.f;
        #pragma unroll
        for (int b = 0; b < BB; ++b) {
            float vmx = sh[b][i], vmn = vmx;
            #pragma unroll
            for (int j = 1; j < KK; ++j) {
                float v = sh[b][i + j];
                vmx = fmaxf(vmx, v);
                vmn = fminf(vmn, v);
            }
            mx |= (vmx > 0.5f ? 1u : 0u) << b;
            mn |= (vmn > 0.5f ? 1u : 0u) << b;

            float tt = sh[b][i + PADR];              // center pixel
            float p  = pred[(size_t)b * HWS + px];
            sp += p; st += tt; si += p * tt;
            // f = t*max(log(sig(p)),-100) + (1-t)*max(log(1-sig(p)),-100)
            float a   = __logf(1.f + __expf(-fabsf(p)));
            float lp  = fmaxf(-(fmaxf(-p, 0.f) + a), -100.f);
            float l1p = fmaxf(-(fmaxf( p, 0.f) + a), -100.f);
            F += tt * lp + (1.f - tt) * l1p;
        }
        hmxb[px] = (unsigned char)mx;
        hmnb[px] = (unsigned char)mn;
        Farr[px] = F;
    }

    #pragma unroll
    for (int off = 32; off > 0; off >>= 1) {
        sp += __shfl_down(sp, off);
        st += __shfl_down(st, off);
        si += __shfl_down(si, off);
    }
    int wave = tid >> 6, lane = tid & 63;
    if (lane == 0) { red[wave][0] = sp; red[wave][1] = st; red[wave][2] = si; }
    __syncthreads();
    if (tid == 0) {
        float a0 = 0.f, a1 = 0.f, a2 = 0.f;
        #pragma unroll
        for (int w = 0; w < 4; ++w) { a0 += red[w][0]; a1 += red[w][1]; a2 += red[w][2]; }
        part1[blockIdx.y * 2 + blockIdx.x] = make_float4(a0, a1, a2, 0.f);
    }
}

// ---- K2: vertical 15-tap via bytewise OR/AND, bs = sum cnt*F (all L2) ----
__global__ __launch_bounds__(256) void ba_k2(
    const unsigned char* __restrict__ hmxb, const unsigned char* __restrict__ hmnb,
    const float* __restrict__ Farr, float* __restrict__ part2)
{
    __shared__ float red[4];
    const int u = blockIdx.x * 256 + threadIdx.x;    // < 73984, exact
    const int y = u / ROWU, xu = u - y * ROWU;

    const unsigned int* mxU = (const unsigned int*)hmxb;
    const unsigned int* mnU = (const unsigned int*)hmnb;
    unsigned int orv = 0u, andv = 0xFFFFFFFFu;
    #pragma unroll
    for (int j = 0; j < KK; ++j) {
        int yy = y - PADR + j; yy = yy < 0 ? 0 : (yy > HH - 1 ? HH - 1 : yy);
        orv  |= mxU[yy * ROWU + xu];
        andv &= mnU[yy * ROWU + xu];
    }
    const unsigned int mask = orv & ~andv;           // bd bits, byte per pixel

    const float4 F4 = *(const float4*)(Farr + 4 * (size_t)u);
    float bs = (float)__popc(mask & 0xFFu)         * F4.x
             + (float)__popc((mask >> 8)  & 0xFFu) * F4.y
             + (float)__popc((mask >> 16) & 0xFFu) * F4.z
             + (float)__popc(mask >> 24)           * F4.w;

    #pragma unroll
    for (int off = 32; off > 0; off >>= 1) bs += __shfl_down(bs, off);
    int wave = threadIdx.x >> 6, lane = threadIdx.x & 63;
    if (lane == 0) red[wave] = bs;
    __syncthreads();
    if (threadIdx.x == 0)
        part2[blockIdx.x] = red[0] + red[1] + red[2] + red[3];
}

// ---- final: sum partials, compose loss ----
__global__ __launch_bounds__(256) void ba_final(
    const float4* __restrict__ part1, const float* __restrict__ part2,
    float* __restrict__ out)
{
    __shared__ float red[4][4];
    float sp = 0.f, st = 0.f, si = 0.f, bs = 0.f;
    for (int i = threadIdx.x; i < NB1; i += 256) {
        float4 v = part1[i];
        sp += v.x; st += v.y; si += v.z;
    }
    for (int i = threadIdx.x; i < NBX; i += 256) bs += part2[i];
    #pragma unroll
    for (int off = 32; off > 0; off >>= 1) {
        sp += __shfl_down(sp, off);
        st += __shfl_down(st, off);
        si += __shfl_down(si, off);
        bs += __shfl_down(bs, off);
    }
    int wave = threadIdx.x >> 6, lane = threadIdx.x & 63;
    if (lane == 0) {
        red[wave][0] = sp; red[wave][1] = st; red[wave][2] = si; red[wave][3] = bs;
    }
    __syncthreads();
    if (threadIdx.x == 0) {
        float a0 = 0.f, a1 = 0.f, a2 = 0.f, a3 = 0.f;
        #pragma unroll
        for (int w = 0; w < 4; ++w) {
            a0 += red[w][0]; a1 += red[w][1]; a2 += red[w][2]; a3 += red[w][3];
        }
        float dice = 1.f - (2.f * a2 + 1.f) / (a0 + a1 + 1.f);
        float bce  = -a3 / (float)((long long)BB * BB * HH * WW);
        out[0] = dice + bce;
    }
}

extern "C" void kernel_launch(void* const* d_in, const int* in_sizes, int n_in,
                              void* d_out, int out_size, void* d_ws, size_t ws_size,
                              hipStream_t stream) {
    const float* pred = (const float*)d_in[0];
    const float* targ = (const float*)d_in[1];
    float* out = (float*)d_out;

    unsigned char* hmxb = (unsigned char*)d_ws;                  // HWS bytes
    unsigned char* hmnb = hmxb + HWS;                            // HWS bytes
    float* Farr  = (float*)(hmnb + HWS);                         // HWS floats
    float4* part1 = (float4*)((char*)Farr + (size_t)HWS * 4);    // NB1 float4
    float* part2 = (float*)(part1 + NB1);                        // NBX floats

    ba_k1<<<dim3(2, HH), 256, 0, stream>>>(pred, targ, hmxb, hmnb, Farr, part1);
    ba_k2<<<NBX, 256, 0, stream>>>(hmxb, hmnb, Farr, part2);
    ba_final<<<1, 256, 0, stream>>>(part1, part2, out);
}